// Round 1
// baseline (325.155 us; speedup 1.0000x reference)
//
#include <hip/hip_runtime.h>
#include <stdint.h>

#define H_DIM 1024
#define B_DIM 16384

typedef unsigned short u16;
typedef short bf16x8 __attribute__((ext_vector_type(8)));
typedef float f32x4 __attribute__((ext_vector_type(4)));

__device__ __forceinline__ u16 f2bf(float f) {
  union { float f; uint32_t u; } v; v.f = f;
  uint32_t r = v.u + 0x7fffu + ((v.u >> 16) & 1u);
  return (u16)(r >> 16);
}

#define GLDS16(gsrc, ldst)                                                                 \
  __builtin_amdgcn_global_load_lds((const __attribute__((address_space(1))) void*)(gsrc),  \
                                   (__attribute__((address_space(3))) void*)(ldst), 16, 0, 0)

// ---------------- fp32 -> bf16 conversion (vectorized, grid-stride) ----------------
__global__ __launch_bounds__(256) void cvt_f32_bf16(const float* __restrict__ in,
                                                    u16* __restrict__ out, int n4) {
  int i = blockIdx.x * blockDim.x + threadIdx.x;
  const int stride = gridDim.x * blockDim.x;
  const float4* __restrict__ in4 = (const float4*)in;
  ushort4* __restrict__ out4 = (ushort4*)out;
  for (; i < n4; i += stride) {
    float4 v = in4[i];
    ushort4 o;
    o.x = f2bf(v.x); o.y = f2bf(v.y); o.z = f2bf(v.z); o.w = f2bf(v.w);
    out4[i] = o;
  }
}

// ---------------- GEMM: C[M,N] = act(A[M,K] @ W[N,K]^T + bias) ----------------
// m97-structure: 128x128 tile, BK=64, 4 waves (2x2), 4x4 16x16x32 bf16 MFMA frags/wave,
// global_load_lds width-16 staging, 2-barrier K-loop.
template <bool RELU, bool HASBIAS, typename OUT>
__global__ __launch_bounds__(256, 2) void gemm_bt(const u16* __restrict__ A,
                                                  const u16* __restrict__ W,
                                                  const float* __restrict__ bias,
                                                  OUT* __restrict__ C,
                                                  int M, int N, int K) {
  __shared__ u16 Ash[128 * 64];
  __shared__ u16 Bsh[128 * 64];
  const int t = threadIdx.x;
  const int w = t >> 6;          // wave 0..3
  const int l = t & 63;          // lane
  const int wr = (w >> 1) * 64;  // wave row offset in tile
  const int wc = (w & 1) * 64;   // wave col offset in tile
  const int l15 = l & 15;
  const int lg = l >> 4;

  const int m0 = blockIdx.y * 128;
  const int n0 = blockIdx.x * 128;

  f32x4 acc[4][4] = {};

  for (int kt = 0; kt < K; kt += 64) {
    __syncthreads();  // previous compute done before overwriting LDS
    // Stage A-tile [128 rows x 64 cols] and B-tile: 1024 16B-chunks each, 4 per thread.
    // LDS dest is wave-uniform base + lane*16 (linear); chunk c -> row c>>3, 16B-col c&7.
#pragma unroll
    for (int i = 0; i < 4; ++i) {
      const int c = w * 256 + i * 64 + l;
      const int row = c >> 3;
      const int col = (c & 7) * 8;
      GLDS16(A + (size_t)(m0 + row) * K + kt + col, &Ash[(w * 256 + i * 64) * 8]);
      GLDS16(W + (size_t)(n0 + row) * K + kt + col, &Bsh[(w * 256 + i * 64) * 8]);
    }
    __syncthreads();  // compiler drains vmcnt(0) before barrier -> tiles ready
#pragma unroll
    for (int ks = 0; ks < 2; ++ks) {
      const int k0 = ks * 32 + lg * 8;
      bf16x8 af[4], bfr[4];
#pragma unroll
      for (int mi = 0; mi < 4; ++mi)
        af[mi] = *(const bf16x8*)&Ash[(wr + mi * 16 + l15) * 64 + k0];
#pragma unroll
      for (int ni = 0; ni < 4; ++ni)
        bfr[ni] = *(const bf16x8*)&Bsh[(wc + ni * 16 + l15) * 64 + k0];
#pragma unroll
      for (int mi = 0; mi < 4; ++mi)
#pragma unroll
        for (int ni = 0; ni < 4; ++ni)
          acc[mi][ni] =
              __builtin_amdgcn_mfma_f32_16x16x32_bf16(af[mi], bfr[ni], acc[mi][ni], 0, 0, 0);
    }
  }

  // Epilogue: C/D layout col = lane&15, row = (lane>>4)*4 + reg (m89/m91-verified).
#pragma unroll
  for (int ni = 0; ni < 4; ++ni) {
    const int col = n0 + wc + ni * 16 + l15;
    float bv = 0.0f;
    if (HASBIAS) bv = bias[col];
#pragma unroll
    for (int mi = 0; mi < 4; ++mi) {
#pragma unroll
      for (int j = 0; j < 4; ++j) {
        const int row = m0 + wr + mi * 16 + lg * 4 + j;
        float v = acc[mi][ni][j] + bv;
        if (RELU) v = fmaxf(v, 0.0f);
        if constexpr (sizeof(OUT) == 2)
          C[(size_t)row * N + col] = (OUT)f2bf(v);
        else
          C[(size_t)row * N + col] = v;
      }
    }
  }
}

// ---------------- fused liquid-neuron update + LayerNorm (one block per row) ----------------
__global__ __launch_bounds__(256) void liquid_ln(const float* __restrict__ h,
                                                 const float* __restrict__ pa,
                                                 const float* __restrict__ ev,
                                                 const float* __restrict__ bias,
                                                 const float* __restrict__ tau,
                                                 const float* __restrict__ decay,
                                                 const float* __restrict__ lnw,
                                                 const float* __restrict__ lnb,
                                                 float* __restrict__ out) {
  const int row = blockIdx.x;
  const int t = threadIdx.x;
  const size_t base = (size_t)row * H_DIM + t * 4;
  const int pcol = t * 4;

  float hf[4], pf[4], ef[4], bf_[4], tf[4], df[4];
  *(float4*)hf = *(const float4*)(h + base);
  *(float4*)pf = *(const float4*)(pa + base);
  *(float4*)ef = *(const float4*)(ev + base);
  *(float4*)bf_ = *(const float4*)(bias + pcol);
  *(float4*)tf = *(const float4*)(tau + pcol);
  *(float4*)df = *(const float4*)(decay + pcol);

  float d[4], s = 0.f, ss = 0.f;
#pragma unroll
  for (int j = 0; j < 4; ++j) {
    const float sig = 1.0f / (1.0f + __expf(-pf[j]));
    const float num = fmaf(-df[j], hf[j], fmaf(1.0f + pf[j], ef[j], bf_[j]));
    const float val = num / (tf[j] * sig);
    d[j] = val;
    s += val;
    ss += val * val;
  }
#pragma unroll
  for (int off = 32; off > 0; off >>= 1) {
    s += __shfl_down(s, off);
    ss += __shfl_down(ss, off);
  }
  __shared__ float rs[4], rss[4];
  const int wv = t >> 6;
  if ((t & 63) == 0) { rs[wv] = s; rss[wv] = ss; }
  __syncthreads();
  const float S = rs[0] + rs[1] + rs[2] + rs[3];
  const float SS = rss[0] + rss[1] + rss[2] + rss[3];
  const float mu = S * (1.0f / H_DIM);
  const float var = SS * (1.0f / H_DIM) - mu * mu;
  const float rstd = rsqrtf(var + 1e-5f);

  float lw[4], lb[4], o[4];
  *(float4*)lw = *(const float4*)(lnw + pcol);
  *(float4*)lb = *(const float4*)(lnb + pcol);
#pragma unroll
  for (int j = 0; j < 4; ++j) o[j] = fmaf((d[j] - mu) * rstd, lw[j], lb[j]);
  *(float4*)(out + base) = *(float4*)o;
}

extern "C" void kernel_launch(void* const* d_in, const int* in_sizes, int n_in,
                              void* d_out, int out_size, void* d_ws, size_t ws_size,
                              hipStream_t stream) {
  // setup_inputs order: t, h, e, W_rec, bias, tau, decay, ln_w, ln_b,
  //                     ce_w1, ce_b1, ce_w2, ce_b2, pm_w, pm_b
  const float* h = (const float*)d_in[1];
  const float* e = (const float*)d_in[2];
  const float* Wrec = (const float*)d_in[3];
  const float* bias = (const float*)d_in[4];
  const float* tau = (const float*)d_in[5];
  const float* decay = (const float*)d_in[6];
  const float* lnw = (const float*)d_in[7];
  const float* lnb = (const float*)d_in[8];
  const float* ce_w1 = (const float*)d_in[9];
  const float* ce_b1 = (const float*)d_in[10];
  const float* ce_w2 = (const float*)d_in[11];
  const float* ce_b2 = (const float*)d_in[12];
  const float* pm_w = (const float*)d_in[13];
  const float* pm_b = (const float*)d_in[14];
  float* out = (float*)d_out;

  char* ws = (char*)d_ws;
  const size_t MB = 1024 * 1024;
  // Layout (aliasing uses stream-ordered lifetimes):
  //  [0,2)MB w1 | [2,4) w2 | [4,6) pm | [6,8) Wrec | [8,40) e_bf | [40,72) h_bf (dead after G1)
  //  [72,104) t1 (dead after G2) | [104,136) ctx (dead after G3)
  //  pa fp32 [40,104) over h_bf+t1 | ev fp32 [104,168) over ctx
  u16* w1b = (u16*)(ws + 0 * MB);
  u16* w2b = (u16*)(ws + 2 * MB);
  u16* w3b = (u16*)(ws + 4 * MB);
  u16* w4b = (u16*)(ws + 6 * MB);
  u16* ebf = (u16*)(ws + 8 * MB);
  u16* hbf = (u16*)(ws + 40 * MB);
  u16* t1 = (u16*)(ws + 72 * MB);
  u16* ctx = (u16*)(ws + 104 * MB);
  float* paf = (float*)(ws + 40 * MB);
  float* evf = (float*)(ws + 104 * MB);

  const int nBH4 = (B_DIM * H_DIM) / 4;
  const int nHH4 = (H_DIM * H_DIM) / 4;
  cvt_f32_bf16<<<2048, 256, 0, stream>>>(h, hbf, nBH4);
  cvt_f32_bf16<<<2048, 256, 0, stream>>>(e, ebf, nBH4);
  cvt_f32_bf16<<<512, 256, 0, stream>>>(ce_w1, w1b, nHH4);
  cvt_f32_bf16<<<512, 256, 0, stream>>>(ce_w2, w2b, nHH4);
  cvt_f32_bf16<<<512, 256, 0, stream>>>(pm_w, w3b, nHH4);
  cvt_f32_bf16<<<512, 256, 0, stream>>>(Wrec, w4b, nHH4);

  dim3 grid(H_DIM / 128, B_DIM / 128);  // (8, 128): x-fastest -> 8 n-tiles share A panel in L2
  gemm_bt<true, true, u16><<<grid, 256, 0, stream>>>(hbf, w1b, ce_b1, t1, B_DIM, H_DIM, H_DIM);
  gemm_bt<false, true, u16><<<grid, 256, 0, stream>>>(t1, w2b, ce_b2, ctx, B_DIM, H_DIM, H_DIM);
  gemm_bt<false, true, float><<<grid, 256, 0, stream>>>(ctx, w3b, pm_b, paf, B_DIM, H_DIM, H_DIM);
  gemm_bt<false, false, float><<<grid, 256, 0, stream>>>(ebf, w4b, nullptr, evf, B_DIM, H_DIM, H_DIM);

  liquid_ln<<<B_DIM, 256, 0, stream>>>(h, paf, evf, bias, tau, decay, lnw, lnb, out);
}

// Round 2
// 251.185 us; speedup vs baseline: 1.2945x; 1.2945x over previous
//
#include <hip/hip_runtime.h>
#include <stdint.h>

#define H_DIM 1024
#define B_DIM 16384

typedef unsigned short u16;
typedef short bf16x8 __attribute__((ext_vector_type(8)));
typedef float f32x4 __attribute__((ext_vector_type(4)));

__device__ __forceinline__ u16 f2bf(float f) {
  union { float f; uint32_t u; } v; v.f = f;
  uint32_t r = v.u + 0x7fffu + ((v.u >> 16) & 1u);
  return (u16)(r >> 16);
}

#define GLDS16(gsrc, ldst)                                                                 \
  __builtin_amdgcn_global_load_lds((const __attribute__((address_space(1))) void*)(gsrc),  \
                                   (__attribute__((address_space(3))) void*)(ldst), 16, 0, 0)

// ---------------- fp32 -> bf16 conversion (vectorized, grid-stride) ----------------
__global__ __launch_bounds__(256) void cvt_f32_bf16(const float* __restrict__ in,
                                                    u16* __restrict__ out, int n4) {
  int i = blockIdx.x * blockDim.x + threadIdx.x;
  const int stride = gridDim.x * blockDim.x;
  const float4* __restrict__ in4 = (const float4*)in;
  ushort4* __restrict__ out4 = (ushort4*)out;
  for (; i < n4; i += stride) {
    float4 v = in4[i];
    ushort4 o;
    o.x = f2bf(v.x); o.y = f2bf(v.y); o.z = f2bf(v.z); o.w = f2bf(v.w);
    out4[i] = o;
  }
}

// ---------------- 256x256-tile deep-pipelined GEMM: C = act(A @ W^T + bias) ----------------
// 512 threads = 8 waves (2M x 4N); per-wave output 128x64 = acc[8][4] of 16x16 frags.
// LDS ring: 4 slots x (A 256x32 + B 256x32) bf16 = 128 KiB. Stage quantum = half-subtile
// (A-part or B-part, 2 global_load_lds per wave). Counted vmcnt(4) once per subtile:
// subtile s+1 complete at top of s+1, subtile s+2 in flight. Swizzle: 16B-slot ^= (row>>1)&3
// applied on ds_read addr AND pre-swizzled global source (gload_lds dest stays linear).
//
// Per-subtile phases (2): P0 {ds aF[0..3]+bF[0..3], stage A(s+2), bar, lgkmcnt0, 16 MFMA, bar}
//                         P1 {ds aF[4..7],          stage B(s+2), bar, lgkmcnt0, 16 MFMA, vmcnt4, bar}

template <int MODE>  // 2 = stage + vmcnt(4); 1 = no stage, vmcnt(0); 0 = no stage, no wait
__device__ __forceinline__ void subtile_step(u16* shp, int slot, int slot2, int aoff, int boff,
                                             int wv, const u16*& pA0, const u16*& pA1,
                                             const u16*& pB0, const u16*& pB1,
                                             f32x4 (&acc)[8][4]) {
  const u16* Ab = shp + slot * 16384 + aoff;
  const u16* Bb = shp + slot * 16384 + 8192 + boff;
  bf16x8 aF[4], bF[4];
#pragma unroll
  for (int i = 0; i < 4; ++i) aF[i] = *(const bf16x8*)(Ab + i * 512);
#pragma unroll
  for (int i = 0; i < 4; ++i) bF[i] = *(const bf16x8*)(Bb + i * 512);
  if (MODE == 2) {
    u16* d = shp + slot2 * 16384 + wv * 1024;
    GLDS16(pA0, d); GLDS16(pA1, d + 512);
    pA0 += 32; pA1 += 32;
  }
  __builtin_amdgcn_s_barrier();
  asm volatile("s_waitcnt lgkmcnt(0)" ::: "memory");
  __builtin_amdgcn_s_setprio(1);
#pragma unroll
  for (int mf = 0; mf < 4; ++mf)
#pragma unroll
    for (int nf = 0; nf < 4; ++nf)
      acc[mf][nf] = __builtin_amdgcn_mfma_f32_16x16x32_bf16(aF[mf], bF[nf], acc[mf][nf], 0, 0, 0);
  __builtin_amdgcn_s_setprio(0);
  __builtin_amdgcn_s_barrier();
#pragma unroll
  for (int i = 0; i < 4; ++i) aF[i] = *(const bf16x8*)(Ab + (4 + i) * 512);
  if (MODE == 2) {
    u16* d = shp + slot2 * 16384 + 8192 + wv * 1024;
    GLDS16(pB0, d); GLDS16(pB1, d + 512);
    pB0 += 32; pB1 += 32;
  }
  __builtin_amdgcn_s_barrier();
  asm volatile("s_waitcnt lgkmcnt(0)" ::: "memory");
  __builtin_amdgcn_s_setprio(1);
#pragma unroll
  for (int mf = 0; mf < 4; ++mf)
#pragma unroll
    for (int nf = 0; nf < 4; ++nf)
      acc[4 + mf][nf] =
          __builtin_amdgcn_mfma_f32_16x16x32_bf16(aF[mf], bF[nf], acc[4 + mf][nf], 0, 0, 0);
  __builtin_amdgcn_s_setprio(0);
  if (MODE == 2) asm volatile("s_waitcnt vmcnt(4)" ::: "memory");
  if (MODE == 1) asm volatile("s_waitcnt vmcnt(0)" ::: "memory");
  __builtin_amdgcn_s_barrier();
}

template <bool RELU, bool HASBIAS, typename OUT>
__global__ __launch_bounds__(512, 2) void gemm256(const u16* __restrict__ A,
                                                  const u16* __restrict__ W,
                                                  const float* __restrict__ bias,
                                                  OUT* __restrict__ C) {
  extern __shared__ u16 sh[];
  const int t = threadIdx.x;
  const int wv = t >> 6, l = t & 63;
  const int wm = wv >> 2, wn = wv & 3;
  const int l15 = l & 15, lg = l >> 4;

  // XCD-chunked bijective swizzle (256 blocks, 8 XCDs): XCD x gets logical [32x, 32x+32).
  const int bid = blockIdx.x;
  const int logical = (bid & 7) * 32 + (bid >> 3);
  const int m0 = (logical >> 2) * 256;  // 64 m-tiles
  const int n0 = (logical & 3) * 256;   // 4 n-tiles (consecutive logical share A panel)

  // ds_read lane offsets (u16 elements). Swizzle f = (row>>1)&3 -> (l15>>1)&3 (frag rows %16==0).
  const int koff = (lg ^ ((l15 >> 1) & 3)) * 8;
  const int aoff = (wm * 128 + l15) * 32 + koff;
  const int boff = (wn * 64 + l15) * 32 + koff;

  // stage lane source (pre-swizzled global addr; LDS dest linear). Per gload: 16 rows x 64B.
  const int rowst = wv * 32 + (l >> 2);                 // instr0 row; instr1 = +16
  const int ksl = ((l & 3) ^ ((l >> 3) & 3)) * 8;       // k-slot swizzle, same for both instrs
  const u16* pA0 = A + (size_t)(m0 + rowst) * H_DIM + ksl;
  const u16* pA1 = pA0 + 16 * H_DIM;
  const u16* pB0 = W + (size_t)(n0 + rowst) * H_DIM + ksl;
  const u16* pB1 = pB0 + 16 * H_DIM;

  f32x4 acc[8][4] = {};

  // Prologue: stage subtiles 0,1 (issue order A0,B0,A1,B1) then vmcnt(4): subtile 0 complete.
  { u16* d = sh + wv * 1024;                 GLDS16(pA0, d); GLDS16(pA1, d + 512); pA0 += 32; pA1 += 32; }
  { u16* d = sh + 8192 + wv * 1024;          GLDS16(pB0, d); GLDS16(pB1, d + 512); pB0 += 32; pB1 += 32; }
  { u16* d = sh + 16384 + wv * 1024;         GLDS16(pA0, d); GLDS16(pA1, d + 512); pA0 += 32; pA1 += 32; }
  { u16* d = sh + 16384 + 8192 + wv * 1024;  GLDS16(pB0, d); GLDS16(pB1, d + 512); pB0 += 32; pB1 += 32; }
  asm volatile("s_waitcnt vmcnt(4)" ::: "memory");
  __builtin_amdgcn_s_barrier();

  // 32 K-subtiles (K=1024). Main loop stages s+2; tail drains 4 -> 0.
  for (int s = 0; s < 30; ++s)
    subtile_step<2>(sh, s & 3, (s + 2) & 3, aoff, boff, wv, pA0, pA1, pB0, pB1, acc);
  subtile_step<1>(sh, 2, 0, aoff, boff, wv, pA0, pA1, pB0, pB1, acc);
  subtile_step<0>(sh, 3, 0, aoff, boff, wv, pA0, pA1, pB0, pB1, acc);

  // Epilogue: C/D layout col = lane&15, row = (lane>>4)*4 + reg (round-1 verified).
  float bv[4];
#pragma unroll
  for (int nf = 0; nf < 4; ++nf)
    bv[nf] = HASBIAS ? bias[n0 + wn * 64 + nf * 16 + l15] : 0.0f;
#pragma unroll
  for (int mf = 0; mf < 8; ++mf) {
#pragma unroll
    for (int nf = 0; nf < 4; ++nf) {
      const int col = n0 + wn * 64 + nf * 16 + l15;
#pragma unroll
      for (int j = 0; j < 4; ++j) {
        const int row = m0 + wm * 128 + mf * 16 + lg * 4 + j;
        float v = acc[mf][nf][j] + bv[nf];
        if (RELU) v = fmaxf(v, 0.0f);
        if constexpr (sizeof(OUT) == 2)
          C[(size_t)row * H_DIM + col] = (OUT)f2bf(v);
        else
          C[(size_t)row * H_DIM + col] = v;
      }
    }
  }
}

// ---------------- fused liquid-neuron update + LayerNorm (one block per row) ----------------
__global__ __launch_bounds__(256) void liquid_ln(const float* __restrict__ h,
                                                 const float* __restrict__ pa,
                                                 const float* __restrict__ ev,
                                                 const float* __restrict__ bias,
                                                 const float* __restrict__ tau,
                                                 const float* __restrict__ decay,
                                                 const float* __restrict__ lnw,
                                                 const float* __restrict__ lnb,
                                                 float* __restrict__ out) {
  const int row = blockIdx.x;
  const int t = threadIdx.x;
  const size_t base = (size_t)row * H_DIM + t * 4;
  const int pcol = t * 4;

  float hf[4], pf[4], ef[4], bf_[4], tf[4], df[4];
  *(float4*)hf = *(const float4*)(h + base);
  *(float4*)pf = *(const float4*)(pa + base);
  *(float4*)ef = *(const float4*)(ev + base);
  *(float4*)bf_ = *(const float4*)(bias + pcol);
  *(float4*)tf = *(const float4*)(tau + pcol);
  *(float4*)df = *(const float4*)(decay + pcol);

  float d[4], s = 0.f, ss = 0.f;
#pragma unroll
  for (int j = 0; j < 4; ++j) {
    const float sig = 1.0f / (1.0f + __expf(-pf[j]));
    const float num = fmaf(-df[j], hf[j], fmaf(1.0f + pf[j], ef[j], bf_[j]));
    const float val = num / (tf[j] * sig);
    d[j] = val;
    s += val;
    ss += val * val;
  }
#pragma unroll
  for (int off = 32; off > 0; off >>= 1) {
    s += __shfl_down(s, off);
    ss += __shfl_down(ss, off);
  }
  __shared__ float rs[4], rss[4];
  const int wv = t >> 6;
  if ((t & 63) == 0) { rs[wv] = s; rss[wv] = ss; }
  __syncthreads();
  const float S = rs[0] + rs[1] + rs[2] + rs[3];
  const float SS = rss[0] + rss[1] + rss[2] + rss[3];
  const float mu = S * (1.0f / H_DIM);
  const float var = SS * (1.0f / H_DIM) - mu * mu;
  const float rstd = rsqrtf(var + 1e-5f);

  float lw[4], lb[4], o[4];
  *(float4*)lw = *(const float4*)(lnw + pcol);
  *(float4*)lb = *(const float4*)(lnb + pcol);
#pragma unroll
  for (int j = 0; j < 4; ++j) o[j] = fmaf((d[j] - mu) * rstd, lw[j], lb[j]);
  *(float4*)(out + base) = *(float4*)o;
}

extern "C" void kernel_launch(void* const* d_in, const int* in_sizes, int n_in,
                              void* d_out, int out_size, void* d_ws, size_t ws_size,
                              hipStream_t stream) {
  // setup_inputs order: t, h, e, W_rec, bias, tau, decay, ln_w, ln_b,
  //                     ce_w1, ce_b1, ce_w2, ce_b2, pm_w, pm_b
  const float* h = (const float*)d_in[1];
  const float* e = (const float*)d_in[2];
  const float* Wrec = (const float*)d_in[3];
  const float* bias = (const float*)d_in[4];
  const float* tau = (const float*)d_in[5];
  const float* decay = (const float*)d_in[6];
  const float* lnw = (const float*)d_in[7];
  const float* lnb = (const float*)d_in[8];
  const float* ce_w1 = (const float*)d_in[9];
  const float* ce_b1 = (const float*)d_in[10];
  const float* ce_w2 = (const float*)d_in[11];
  const float* ce_b2 = (const float*)d_in[12];
  const float* pm_w = (const float*)d_in[13];
  const float* pm_b = (const float*)d_in[14];
  float* out = (float*)d_out;

  char* ws = (char*)d_ws;
  const size_t MB = 1024 * 1024;
  u16* w1b = (u16*)(ws + 0 * MB);
  u16* w2b = (u16*)(ws + 2 * MB);
  u16* w3b = (u16*)(ws + 4 * MB);
  u16* w4b = (u16*)(ws + 6 * MB);
  u16* ebf = (u16*)(ws + 8 * MB);
  u16* hbf = (u16*)(ws + 40 * MB);
  u16* t1 = (u16*)(ws + 72 * MB);
  u16* ctx = (u16*)(ws + 104 * MB);
  float* paf = (float*)(ws + 40 * MB);
  float* evf = (float*)(ws + 104 * MB);

  const int nBH4 = (B_DIM * H_DIM) / 4;
  const int nHH4 = (H_DIM * H_DIM) / 4;
  cvt_f32_bf16<<<2048, 256, 0, stream>>>(h, hbf, nBH4);
  cvt_f32_bf16<<<2048, 256, 0, stream>>>(e, ebf, nBH4);
  cvt_f32_bf16<<<512, 256, 0, stream>>>(ce_w1, w1b, nHH4);
  cvt_f32_bf16<<<512, 256, 0, stream>>>(ce_w2, w2b, nHH4);
  cvt_f32_bf16<<<512, 256, 0, stream>>>(pm_w, w3b, nHH4);
  cvt_f32_bf16<<<512, 256, 0, stream>>>(Wrec, w4b, nHH4);

  // 128 KiB dynamic LDS per block
  const int LDS_BYTES = 131072;
  hipFuncSetAttribute((const void*)gemm256<true, true, u16>,
                      hipFuncAttributeMaxDynamicSharedMemorySize, LDS_BYTES);
  hipFuncSetAttribute((const void*)gemm256<false, true, u16>,
                      hipFuncAttributeMaxDynamicSharedMemorySize, LDS_BYTES);
  hipFuncSetAttribute((const void*)gemm256<false, true, float>,
                      hipFuncAttributeMaxDynamicSharedMemorySize, LDS_BYTES);
  hipFuncSetAttribute((const void*)gemm256<false, false, float>,
                      hipFuncAttributeMaxDynamicSharedMemorySize, LDS_BYTES);

  const int NWG = (B_DIM / 256) * (H_DIM / 256);  // 256 blocks = 1 per CU
  gemm256<true, true, u16><<<NWG, 512, LDS_BYTES, stream>>>(hbf, w1b, ce_b1, t1);
  gemm256<false, true, u16><<<NWG, 512, LDS_BYTES, stream>>>(t1, w2b, ce_b2, ctx);
  gemm256<false, true, float><<<NWG, 512, LDS_BYTES, stream>>>(ctx, w3b, pm_b, paf);
  gemm256<false, false, float><<<NWG, 512, LDS_BYTES, stream>>>(ebf, w4b, nullptr, evf);

  liquid_ln<<<B_DIM, 256, 0, stream>>>(h, paf, evf, bias, tau, decay, lnw, lnb, out);
}